// Round 1
// baseline (397.152 us; speedup 1.0000x reference)
//
#include <hip/hip_runtime.h>

// QuantizedLinear: out = fakequant(x) @ ((qw - zp)*scale).T + bias
// R4: GEMM ported to the 256^2 8-phase counted-vmcnt template (T3+T4+T5):
//   BM=BN=256, BK=128 int8, 512 threads (8 waves, 2Mx4N), per-wave 128x64.
//   Per K-tile: 4 C-quadrant phases x 16 mfma_i32_16x16x64_i8. Staging in
//   half-tile units (A0/A1/B0/B1, 2x global_load_lds rounds each), one unit
//   issued per phase ~5 phases ahead; waits are counted (vmcnt 8/6), never 0
//   in steady state. Raw s_barrier (no __syncthreads drain). T2 XOR swizzle
//   kept verbatim from R3 (measured 0 bank conflicts).
//   M = B*S = 8192, N = D_OUT = 4096, K = D_IN = 4096.

typedef __attribute__((ext_vector_type(4))) int int4v;

#define BM 256
#define BN 256
#define BK 128   // int8 per K-block; 128 B per LDS row

// ---- fake-quant x -> int8, lane-contiguous: 1 float4 per thread ----
__global__ __launch_bounds__(256) void quant_x_kernel(
    const float4* __restrict__ x, unsigned int* __restrict__ xq,
    const float* __restrict__ act_scale_p, const int* __restrict__ act_zp_p,
    int n4)
{
    int g = blockIdx.x * blockDim.x + threadIdx.x;
    if (g >= n4) return;
    const float s   = act_scale_p[0];
    const float azp = (float)act_zp_p[0];
    const float lo = -azp, hi = 255.0f - azp;
    float4 v = x[g];
    float f0 = fminf(fmaxf(rintf(v.x / s), lo), hi);   // IEEE div+RNE = jnp.round(x/s)
    float f1 = fminf(fmaxf(rintf(v.y / s), lo), hi);
    float f2 = fminf(fmaxf(rintf(v.z / s), lo), hi);
    float f3 = fminf(fmaxf(rintf(v.w / s), lo), hi);
    unsigned int b0 = (unsigned int)(int)f0 & 0xff;
    unsigned int b1 = (unsigned int)(int)f1 & 0xff;
    unsigned int b2 = (unsigned int)(int)f2 & 0xff;
    unsigned int b3 = (unsigned int)(int)f3 & 0xff;
    xq[g] = b0 | (b1 << 8) | (b2 << 16) | (b3 << 24);
}

// ---- weight integer part -> int8, lane-contiguous: 1 int4 per thread ----
__global__ __launch_bounds__(256) void quant_w_kernel(
    const int4* __restrict__ qw, unsigned int* __restrict__ wq,
    const int* __restrict__ zp_p, int n4)
{
    int g = blockIdx.x * blockDim.x + threadIdx.x;
    if (g >= n4) return;
    const int zp = zp_p[0];
    int4 v = qw[g];
    unsigned int b0 = (unsigned int)(v.x - zp) & 0xff;
    unsigned int b1 = (unsigned int)(v.y - zp) & 0xff;
    unsigned int b2 = (unsigned int)(v.z - zp) & 0xff;
    unsigned int b3 = (unsigned int)(v.w - zp) & 0xff;
    wq[g] = b0 | (b1 << 8) | (b2 << 16) | (b3 << 24);
}

// ---- int8 GEMM, B^T input (w is [N][K]) ----
// LDS swizzle (unchanged from R3): 16B chunk c of row r stored at slot c^(r&7);
// staging keeps dst = uniform base + tid*16 (the XOR is applied to the global
// source column), reads XOR the chunk index. Measured 0 bank conflicts.
#define ASYNC_CP16(gp, lp)                                                      \
    __builtin_amdgcn_global_load_lds(                                           \
        (const __attribute__((address_space(1))) unsigned int*)(gp),            \
        (__attribute__((address_space(3))) unsigned int*)(lp), 16, 0, 0)

__global__ __launch_bounds__(512, 2) void gemm_i8_kernel(
    const signed char* __restrict__ A,   // [M][K] int8 (xi)
    const signed char* __restrict__ B,   // [N][K] int8 (wi)
    const float* __restrict__ bias,
    const float* __restrict__ scale_p, const float* __restrict__ act_scale_p,
    float* __restrict__ C, int M, int N, int K)
{
    __shared__ __align__(16) signed char As[2][BM * BK];   // 2 x 32 KB
    __shared__ __align__(16) signed char Bs[2][BN * BK];   // 2 x 32 KB

    const int tid  = threadIdx.x;
    const int lane = tid & 63;
    const int wave = tid >> 6;
    const int wm = wave >> 2;            // 0..1 (M-half of wave grid)
    const int wn = wave & 3;             // 0..3 (N-quarter)
    const int bm = blockIdx.y * BM;
    const int bn = blockIdx.x * BN;

    // staging: one round = 512 threads x 16 B = 8 KB = 64 rows of 128 B.
    // half-tile unit = 128 rows = 2 rounds.
    const int srow = tid >> 3;                       // 0..63 within a round
    const int scol = ((tid & 7) ^ (srow & 7)) * 16;  // XOR applied to source
    const signed char* aP = A + (size_t)(bm + srow) * K + scol;
    const signed char* bP = B + (size_t)(bn + srow) * K + scol;

    const int fr = lane & 15;            // fragment row (m or n)
    const int g4 = lane >> 4;            // k-chunk group 0..3
    const int x7 = fr & 7;
    const int ko0 = ((0 * 4 + g4) ^ x7) * 16;   // k-step 0 chunk byte
    const int ko1 = ((1 * 4 + g4) ^ x7) * 16;   // k-step 1 chunk byte

    // per-thread LDS read byte bases. Row mapping (address-half aligned):
    //   A row(i) = (i>>2)*128 + wm*64 + (i&3)*16 + fr
    //   B row(j) = (j>>1)*128 + wn*32 + (j&1)*16 + fr
    const int aRd = (wm * 64 + fr) * BK;
    const int bRd = (wn * 32 + fr) * BK;

    int4v acc[8][4] = {};
    const int NT = K / BK;

    // stage one 64-row round of half H (0/1), tile T, into LDS buffer base L
#define SR(gp, L, H, R, T)                                                     \
    ASYNC_CP16((gp) + (size_t)((H) * 128 + (R) * 64) * K + (size_t)(T) * BK,   \
               (L) + (H) * 16384 + (R) * 8192 + tid * 16)
#define SU(gp, L, H, T) do { SR(gp, L, H, 0, T); SR(gp, L, H, 1, T); } while (0)

    // ---- prologue: issue A0(0) B0(0) B1(0) A1(0) -> buf0; A0(1) B0(1) -> buf1
    SU(aP, As[0], 0, 0);
    SU(bP, Bs[0], 0, 0);
    SU(bP, Bs[0], 1, 0);
    SU(aP, As[0], 1, 0);
    if (NT > 1) {
        SU(aP, As[1], 0, 1);
        SU(bP, Bs[1], 0, 1);
        asm volatile("s_waitcnt vmcnt(6)");   // A0/B0/B1(0) done; 3 units fly
    } else {
        asm volatile("s_waitcnt vmcnt(2)");   // A0/B0/B1(0) done; A1(0) flies
    }
    __builtin_amdgcn_s_barrier();

#define LDA(RH)                                                                \
    _Pragma("unroll") for (int i2 = 0; i2 < 4; ++i2) {                         \
        af[i2][0] = *(const int4v*)&cA[aRd + (RH) * 16384 + i2 * 2048 + ko0];  \
        af[i2][1] = *(const int4v*)&cA[aRd + (RH) * 16384 + i2 * 2048 + ko1];  \
    }
#define LDB(CH)                                                                \
    _Pragma("unroll") for (int j2 = 0; j2 < 2; ++j2) {                         \
        bf[j2][0] = *(const int4v*)&cB[bRd + (CH) * 16384 + j2 * 2048 + ko0];  \
        bf[j2][1] = *(const int4v*)&cB[bRd + (CH) * 16384 + j2 * 2048 + ko1];  \
    }
#define MMA(RH, CH)                                                            \
    _Pragma("unroll") for (int ks = 0; ks < 2; ++ks)                           \
    _Pragma("unroll") for (int i2 = 0; i2 < 4; ++i2)                           \
    _Pragma("unroll") for (int j2 = 0; j2 < 2; ++j2)                           \
        acc[(RH) * 4 + i2][(CH) * 2 + j2] =                                    \
            __builtin_amdgcn_mfma_i32_16x16x64_i8(                             \
                af[i2][ks], bf[j2][ks], acc[(RH) * 4 + i2][(CH) * 2 + j2],     \
                0, 0, 0);

#pragma unroll 2
    for (int t = 0; t < NT; ++t) {
        signed char* cA = As[t & 1];
        signed char* cB = Bs[t & 1];
        signed char* nA = As[(t & 1) ^ 1];
        signed char* nB = Bs[(t & 1) ^ 1];
        const bool p1 = (t + 1 < NT);
        const bool p2 = (t + 2 < NT);
        int4v af[4][2], bf[2][2];

        // P0: Q(0,0) uses A0,B0(t); issue B1(t+1) -> other buf
        LDA(0); LDB(0);
        if (p1) SU(bP, nB, 1, t + 1);
        __builtin_amdgcn_s_barrier();
        asm volatile("s_waitcnt lgkmcnt(0)");
        __builtin_amdgcn_s_setprio(1);
        MMA(0, 0);
        __builtin_amdgcn_s_setprio(0);
        __builtin_amdgcn_s_barrier();

        // P1: Q(0,1) uses B1(t); issue A1(t+1); tail: wait A1(t) (mid-tile)
        LDB(1);
        if (p1) SU(aP, nA, 1, t + 1);
        __builtin_amdgcn_s_barrier();
        asm volatile("s_waitcnt lgkmcnt(0)");
        __builtin_amdgcn_s_setprio(1);
        MMA(0, 1);
        __builtin_amdgcn_s_setprio(0);
        if (p1) asm volatile("s_waitcnt vmcnt(8)");  // A1(t) done; 4 units fly
        else    asm volatile("s_waitcnt vmcnt(0)");  // last tile: drain
        __builtin_amdgcn_s_barrier();

        // P2: Q(1,0) uses A1(t), re-reads B0(t); issue A0(t+2) -> this buf
        //     (A0 region free since P0's reads drained at P0's lgkmcnt+barrier)
        LDA(1); LDB(0);
        if (p2) SU(aP, cA, 0, t + 2);
        __builtin_amdgcn_s_barrier();
        asm volatile("s_waitcnt lgkmcnt(0)");
        __builtin_amdgcn_s_setprio(1);
        MMA(1, 0);
        __builtin_amdgcn_s_setprio(0);
        __builtin_amdgcn_s_barrier();

        // P3: Q(1,1) re-reads B1(t); issue B0(t+2) -> this buf (free after P2);
        //     tail: boundary wait for A0/B0/B1(t+1)
        LDB(1);
        if (p2) SU(bP, cB, 0, t + 2);
        __builtin_amdgcn_s_barrier();
        asm volatile("s_waitcnt lgkmcnt(0)");
        __builtin_amdgcn_s_setprio(1);
        MMA(1, 1);
        __builtin_amdgcn_s_setprio(0);
        if (p1) {
            if (p2) asm volatile("s_waitcnt vmcnt(6)"); // A1(t+1),A0/B0(t+2) fly
            else    asm volatile("s_waitcnt vmcnt(2)"); // only A1(t+1) flies
        }
        __builtin_amdgcn_s_barrier();
    }

    // epilogue: C/D layout col=lane&15, row=(lane>>4)*4+reg (dtype-independent)
    const float sc = scale_p[0] * act_scale_p[0];
    const int crow = (lane >> 4) * 4;
    const int ccol = lane & 15;
#pragma unroll
    for (int i = 0; i < 8; ++i) {
        const int m = bm + (i >> 2) * 128 + wm * 64 + (i & 3) * 16 + crow;
#pragma unroll
        for (int j = 0; j < 4; ++j) {
            const int n = bn + (j >> 1) * 128 + wn * 32 + (j & 1) * 16 + ccol;
            const float bv = bias[n];
#pragma unroll
            for (int r = 0; r < 4; ++r) {
                C[(size_t)(m + r) * N + n] = (float)acc[i][j][r] * sc + bv;
            }
        }
    }
}

extern "C" void kernel_launch(void* const* d_in, const int* in_sizes, int n_in,
                              void* d_out, int out_size, void* d_ws, size_t ws_size,
                              hipStream_t stream) {
    const float* x         = (const float*)d_in[0];
    const int*   qw        = (const int*)  d_in[1];
    const float* scale     = (const float*)d_in[2];
    const int*   zp        = (const int*)  d_in[3];
    const float* bias      = (const float*)d_in[4];
    const float* act_scale = (const float*)d_in[5];
    const int*   act_zp    = (const int*)  d_in[6];
    float* out = (float*)d_out;

    const int D_OUT = in_sizes[4];            // bias length
    const int D_IN  = in_sizes[1] / D_OUT;    // qweight is [D_OUT][D_IN]
    const int M = in_sizes[0] / D_IN;
    const int N = D_OUT, K = D_IN;

    signed char* xq = (signed char*)d_ws;                  // [M][K] int8
    signed char* wq = xq + (size_t)M * K;                  // [N][K] int8

    const int n4x = (M * K) / 4;
    quant_x_kernel<<<(n4x + 255) / 256, 256, 0, stream>>>(
        (const float4*)x, (unsigned int*)xq, act_scale, act_zp, n4x);

    const int n4w = (N * K) / 4;
    quant_w_kernel<<<(n4w + 255) / 256, 256, 0, stream>>>(
        (const int4*)qw, (unsigned int*)wq, zp, n4w);

    dim3 grid(N / BN, M / BM);
    gemm_i8_kernel<<<grid, 512, 0, stream>>>(xq, wq, bias, scale, act_scale,
                                             out, M, N, K);
}